// Round 7
// baseline (586.549 us; speedup 1.0000x reference)
//
#include <hip/hip_runtime.h>

#define V_NODES 327696
#define E_EDGES 1966080
#define C_DIM   64
#define G_NUM   4
#define EPS_GN  1e-5f
#define N_TILES (V_NODES/16)      // 20481 exact
#define SAGE_BLOCKS 2048
#define WAVES_TOTAL (SAGE_BLOCKS*4)
#define FILL_BLOCKS 512
#define H_BLOCKS 2048
#define NB_SCAN 1281              // ceil(V/256)
#define CH_SCAN2 6                // ceil(NB_SCAN/256)
#define HIST_BLOCKS 64
#define HP 5121                   // ceil(V/64); 64*5121 >= V
#define STAT_BLOCKS 512
#define K1_THREADS 512
#define ST_STRIDE2 (STAT_BLOCKS*K1_THREADS)   // 262144
#define PW 520                    // partial row width (floats)

typedef short bf16x8 __attribute__((ext_vector_type(8)));
typedef float f32x4  __attribute__((ext_vector_type(4)));
typedef unsigned uintx4 __attribute__((ext_vector_type(4)));
typedef int intx4 __attribute__((ext_vector_type(4)));
typedef unsigned short u16x2 __attribute__((ext_vector_type(2)));

__device__ __forceinline__ unsigned short f2bf(float f) {   // RNE f32 -> bf16
    unsigned u = __float_as_uint(f);
    return (unsigned short)((u + 0x7FFFu + ((u >> 16) & 1u)) >> 16);
}
// monotone-u16 encoding of bf16 bits: order(enc)==order(value)
__device__ __forceinline__ unsigned short encbf(float f) {
    unsigned short b = f2bf(f);
    return b ^ (unsigned short)(0x8000u | ((b >> 15) * 0x7FFFu));
}
__device__ __forceinline__ unsigned decp(unsigned e) {      // packed decode x2
    unsigned s = e & 0x80008000u;
    unsigned m = (s >> 15) * 0x7FFFu;
    return e ^ ~m;
}
__device__ __forceinline__ unsigned pkmaxu(unsigned a, unsigned b) {
    u16x2 xa = __builtin_bit_cast(u16x2, a);
    u16x2 xb = __builtin_bit_cast(u16x2, b);
    u16x2 r  = __builtin_elementwise_max(xa, xb);           // v_pk_max_u16
    return __builtin_bit_cast(unsigned, r);
}

// ---------------------------------------------------------------------------
// K1 (merged, 512-thread blocks):
//  blocks [0,HIST_BLOCKS): partition-owner LDS histogram + rank (NO global
//    atomics — rank from LDS atomicAdd return; hist written coalesced)
//  blocks [HIST_BLOCKS,..): per-(g,c) sum/sumsq/count of x, 4-deep batched
//    float4 loads, LDS reduce, coalesced partial-row write (NO global atomics)
// ---------------------------------------------------------------------------
__global__ __launch_bounds__(512) void k1(const float* __restrict__ x,
                                          const int* __restrict__ batch,
                                          const int* __restrict__ ei,
                                          unsigned short* __restrict__ rank,
                                          int* __restrict__ hist,
                                          float* __restrict__ partial1) {
    __shared__ int lh[HP];                         // 20.5 KB
    __shared__ float red_s[256], red_q[256], red_c[G_NUM];
    const int t = threadIdx.x;

    if (blockIdx.x < HIST_BLOCKS) {
        const int base = blockIdx.x * HP;
        const unsigned range = (unsigned)((V_NODES - base < HP) ? (V_NODES - base) : HP);
        for (int j = t; j < HP; j += K1_THREADS) lh[j] = 0;
        __syncthreads();
        const int* dst = ei + E_EDGES;
        // 960 x4-groups per thread-stride; unroll 2 -> 8 dst values in flight
        for (int it = 0; it < E_EDGES/(K1_THREADS*4); it += 2) {
            int e0 = (it*K1_THREADS + t) * 4;
            int e1 = e0 + K1_THREADS*4;
            intx4 a = *(const intx4*)(dst + e0);
            intx4 b = *(const intx4*)(dst + e1);
            #pragma unroll
            for (int j = 0; j < 4; j++) {
                unsigned da = (unsigned)a[j] - (unsigned)base;
                if (da < range) rank[e0 + j] = (unsigned short)atomicAdd(&lh[da], 1);
            }
            #pragma unroll
            for (int j = 0; j < 4; j++) {
                unsigned db = (unsigned)b[j] - (unsigned)base;
                if (db < range) rank[e1 + j] = (unsigned short)atomicAdd(&lh[db], 1);
            }
        }
        __syncthreads();
        for (int j = t; j < (int)range; j += K1_THREADS) hist[base + j] = lh[j];
        return;
    }

    // ---------------- stats path ----------------
    if (t < 256) { red_s[t] = 0.0f; red_q[t] = 0.0f; }
    if (t < G_NUM) red_c[t] = 0.0f;
    __syncthreads();
    const int i0 = (blockIdx.x - HIST_BLOCKS) * K1_THREADS + t;
    const int c4 = (i0 & 15) << 2;                 // loop-invariant channel quad
    const bool cntr = (c4 == 0);
    const float4* x4p = (const float4*)x;
    float4 su = {0,0,0,0}, qu = {0,0,0,0};
    float rc = 0.0f;
    int gcur = -1;
    const int total = V_NODES * 16;

#define FLUSH() { \
    atomicAdd(&red_s[(gcur<<6)+c4],   su.x); atomicAdd(&red_q[(gcur<<6)+c4],   qu.x); \
    atomicAdd(&red_s[(gcur<<6)+c4+1], su.y); atomicAdd(&red_q[(gcur<<6)+c4+1], qu.y); \
    atomicAdd(&red_s[(gcur<<6)+c4+2], su.z); atomicAdd(&red_q[(gcur<<6)+c4+2], qu.z); \
    atomicAdd(&red_s[(gcur<<6)+c4+3], su.w); atomicAdd(&red_q[(gcur<<6)+c4+3], qu.w); \
    if (cntr) atomicAdd(&red_c[gcur], rc); }
#define STEP(G, VAL) { \
    if ((G) != gcur) { \
        if (gcur >= 0) FLUSH(); \
        gcur = (G); su = (float4){0,0,0,0}; qu = (float4){0,0,0,0}; rc = 0.0f; } \
    su.x += (VAL).x; su.y += (VAL).y; su.z += (VAL).z; su.w += (VAL).w; \
    qu.x = fmaf((VAL).x,(VAL).x,qu.x); qu.y = fmaf((VAL).y,(VAL).y,qu.y); \
    qu.z = fmaf((VAL).z,(VAL).z,qu.z); qu.w = fmaf((VAL).w,(VAL).w,qu.w); \
    rc += 1.0f; }

    int i = i0;
    for (; i + 3*ST_STRIDE2 < total; i += 4*ST_STRIDE2) {
        int ga = batch[i >> 4];
        int gb = batch[(i +   ST_STRIDE2) >> 4];
        int gg = batch[(i + 2*ST_STRIDE2) >> 4];
        int gd = batch[(i + 3*ST_STRIDE2) >> 4];
        float4 A = x4p[i];
        float4 B = x4p[i +   ST_STRIDE2];
        float4 C = x4p[i + 2*ST_STRIDE2];
        float4 D = x4p[i + 3*ST_STRIDE2];
        STEP(ga, A) STEP(gb, B) STEP(gg, C) STEP(gd, D)
    }
    for (; i < total; i += ST_STRIDE2) {
        int g = batch[i >> 4];
        float4 A = x4p[i];
        STEP(g, A)
    }
    if (gcur >= 0) FLUSH();
#undef STEP
#undef FLUSH
    __syncthreads();
    float* row = partial1 + (size_t)(blockIdx.x - HIST_BLOCKS) * PW;
    if (t < 256) { row[t] = red_s[t]; row[256 + t] = red_q[t]; }
    if (t < G_NUM) row[512 + t] = red_c[t];
}

// ---------------------------------------------------------------------------
// k_red: reduce partial rows -> sums (wave per entry, coalesced-in-e reads)
// ---------------------------------------------------------------------------
__global__ __launch_bounds__(256) void k_red(const float* __restrict__ partial,
                                             int nblocks, int nent,
                                             float* __restrict__ outs,
                                             float* __restrict__ outc) {
    int e = blockIdx.x * 4 + (threadIdx.x >> 6);
    int lane = threadIdx.x & 63;
    if (e >= nent) return;
    float s = 0.0f;
    for (int b = lane; b < nblocks; b += 64) s += partial[(size_t)b * PW + e];
    #pragma unroll
    for (int off = 1; off < 64; off <<= 1) s += __shfl_xor(s, off);
    if (lane == 0) { if (e < 512) outs[e] = s; else outc[e - 512] = s; }
}

// ---------------------------------------------------------------------------
// Scan level 1: per-block (256-entry) sums of hist
// ---------------------------------------------------------------------------
__global__ __launch_bounds__(256) void k_scan1(const int* __restrict__ hist,
                                               int* __restrict__ bsum) {
    __shared__ int s[256];
    int i = blockIdx.x * 256 + threadIdx.x;
    s[threadIdx.x] = (i < V_NODES) ? hist[i] : 0;
    __syncthreads();
    for (int off = 128; off > 0; off >>= 1) {
        if (threadIdx.x < off) s[threadIdx.x] += s[threadIdx.x + off];
        __syncthreads();
    }
    if (threadIdx.x == 0) bsum[blockIdx.x] = s[0];
}

// ---------------------------------------------------------------------------
// K2: block 0 = GraphNorm affine fold (+ optional swizzled weight prep);
//     block 1 (if launched) = exclusive scan of the 1281 block sums
// ---------------------------------------------------------------------------
__global__ __launch_bounds__(256) void k_params(const float* __restrict__ sum,
                                                const float* __restrict__ sumsq,
                                                const float* __restrict__ cnt,
                                                const float* __restrict__ w,
                                                const float* __restrict__ b,
                                                const float* __restrict__ ms,
                                                float* __restrict__ scale,
                                                float* __restrict__ shift,
                                                const float* __restrict__ Wl,
                                                const float* __restrict__ Wr,
                                                char* __restrict__ gWsw,
                                                int do_wt,
                                                int* __restrict__ bsum) {
    if (blockIdx.x == 0) {
        int t = threadIdx.x;            // t = g*64 + c
        int g = t >> 6, c = t & 63;
        float n    = cnt[g];
        float mean = sum[t] / n;
        float msq  = sumsq[t] / n;
        float m    = ms[c];
        float var  = msq - 2.0f*m*mean*mean + m*m*mean*mean;
        float inv  = rsqrtf(var + EPS_GN);
        float sc   = w[c] * inv;
        scale[t] = sc;
        shift[t] = b[c] - mean * m * sc;
        if (do_wt) {
            for (int i = threadIdx.x; i < C_DIM*C_DIM; i += 256) {
                int k = i >> 6, col = i & 63;          // W[k][col]
                int boff = (col*128 + k*2) ^ ((col & 7) << 4);
                *(unsigned short*)(gWsw + boff)        = f2bf(Wl[i]);
                *(unsigned short*)(gWsw + 8192 + boff) = f2bf(Wr[i]);
            }
        }
    } else {                            // scan of bsum[0..NB_SCAN)
        __shared__ int s[256];
        int t = threadIdx.x;
        int loc[CH_SCAN2];
        int mysum = 0;
        #pragma unroll
        for (int j = 0; j < CH_SCAN2; j++) {
            int idx = t * CH_SCAN2 + j;
            loc[j] = (idx < NB_SCAN) ? bsum[idx] : 0;
            mysum += loc[j];
        }
        s[t] = mysum;
        __syncthreads();
        for (int off = 1; off < 256; off <<= 1) {      // Hillis-Steele inclusive
            int tmp = (t >= off) ? s[t - off] : 0;
            __syncthreads();
            s[t] += tmp;
            __syncthreads();
        }
        int ex = s[t] - mysum;                          // exclusive prefix
        #pragma unroll
        for (int j = 0; j < CH_SCAN2; j++) {
            int idx = t * CH_SCAN2 + j;
            if (idx < NB_SCAN) { bsum[idx] = ex; ex += loc[j]; }
        }
    }
}

// ---------------------------------------------------------------------------
// Scan level 3: per-block exclusive scan + block offset -> offs
// ---------------------------------------------------------------------------
__global__ __launch_bounds__(256) void k_scan3(const int* __restrict__ hist,
                                               const int* __restrict__ bsum,
                                               int* __restrict__ offs) {
    __shared__ int s[256];
    int t = threadIdx.x;
    int i = blockIdx.x * 256 + t;
    int v = (i < V_NODES) ? hist[i] : 0;
    s[t] = v;
    __syncthreads();
    for (int off = 1; off < 256; off <<= 1) {
        int tmp = (t >= off) ? s[t - off] : 0;
        __syncthreads();
        s[t] += tmp;
        __syncthreads();
    }
    int ex = s[t] - v + bsum[blockIdx.x];
    if (i < V_NODES) offs[i] = ex;
    if (i == 0) offs[V_NODES] = E_EDGES;
}

// ---------------------------------------------------------------------------
// K3 (merged): blocks [0,FILL_BLOCKS) do atomic-free CSR fill via rank;
//              blocks [FILL_BLOCKS, ...) compute henc = enc(bf16(norm1(x)))
// ---------------------------------------------------------------------------
__global__ __launch_bounds__(256) void k_h_fill(const float* __restrict__ x,
                                                const int* __restrict__ batch,
                                                const float* __restrict__ scale1,
                                                const float* __restrict__ shift1,
                                                unsigned short* __restrict__ henc,
                                                const int* __restrict__ ei,
                                                const unsigned short* __restrict__ rank,
                                                const int* __restrict__ offs,
                                                int* __restrict__ slots) {
    if (blockIdx.x < FILL_BLOCKS) {
        int stride = FILL_BLOCKS * 256;
        for (int e = blockIdx.x * 256 + threadIdx.x; e < E_EDGES; e += stride) {
            int src = ei[e];
            int d   = ei[E_EDGES + e];
            slots[offs[d] + (int)rank[e]] = src;
        }
        return;
    }
    __shared__ float sc[256], sh[256];
    sc[threadIdx.x] = scale1[threadIdx.x];
    sh[threadIdx.x] = shift1[threadIdx.x];
    __syncthreads();
    const int total = V_NODES * 16;           // float4 chunks
    int bid = blockIdx.x - FILL_BLOCKS;
    int stride = H_BLOCKS * 256;
    const float4* x4 = (const float4*)x;
    ushort4* h4 = (ushort4*)henc;
    for (int i = bid * 256 + threadIdx.x; i < total; i += stride) {
        int v  = i >> 4;
        int c4 = (i & 15) << 2;
        int g  = batch[v];
        int p  = (g << 6) | c4;
        float4 val = x4[i];
        ushort4 o;
        o.x = encbf(fmaf(val.x, sc[p],   sh[p]));
        o.y = encbf(fmaf(val.y, sc[p+1], sh[p+1]));
        o.z = encbf(fmaf(val.z, sc[p+2], sh[p+2]));
        o.w = encbf(fmaf(val.w, sc[p+3], sh[p+3]));
        h4[i] = o;
    }
}

// ---------------------------------------------------------------------------
// K4: fused gather-max + dual GEMM (MFMA) + residual/ReLU + stats2 partials.
// ---------------------------------------------------------------------------
__global__ __launch_bounds__(256) void k_sage(const unsigned short* __restrict__ henc,
                                              const float* __restrict__ x,
                                              const int* __restrict__ batch,
                                              const int* __restrict__ offs,
                                              const int* __restrict__ slots,
                                              const char* __restrict__ gWsw,
                                              const float* __restrict__ bl,
                                              float* __restrict__ out,
                                              float* __restrict__ partial2) {
    __shared__ char lds_w[16384];          // Wl swizzled at 0, Wr at 8192
    __shared__ float red_s[256], red_q[256];
    {
        const float4* wsrc = (const float4*)gWsw;
        float4* wdst = (float4*)lds_w;
        for (int t = threadIdx.x; t < 1024; t += 256) wdst[t] = wsrc[t];
    }
    red_s[threadIdx.x] = 0.0f; red_q[threadIdx.x] = 0.0f;
    __syncthreads();

    const int lane = threadIdx.x & 63;
    const int wid  = threadIdx.x >> 6;
    const int lg = lane >> 4, lr = lane & 15;
    const char* hbase = (const char*)henc;

    float blv[4];
    #pragma unroll
    for (int cb = 0; cb < 4; cb++) blv[cb] = bl[cb*16 + lr];

    float su[4] = {0,0,0,0}, qu[4] = {0,0,0,0};
    int gc = -1;

    const int gwave = blockIdx.x * 4 + wid;
    for (int tile = gwave; tile < N_TILES; tile += WAVES_TOTAL) {
        const int rbase = tile << 4;
        const int myrow = rbase + lr;
        int st = offs[myrow];
        int en = offs[myrow + 1];

        // root-h loads early (independent of gather)
        const char* hr = hbase + ((unsigned)myrow << 7);
        uintx4 r0 = *(const uintx4*)(hr + lg*16);
        uintx4 r1 = *(const uintx4*)(hr + 64 + lg*16);

        // ---- gather-max: 8 edges/row/step, 16 h-loads in flight ----
        uintx4 mA0 = {0,0,0,0}, mA1 = {0,0,0,0};
        uintx4 mB0 = {0,0,0,0}, mB1 = {0,0,0,0};
        for (int i = st & ~7; __ballot(i < en) != 0ull; i += 8) {
            intx4 qa = *(const intx4*)(slots + i);
            intx4 qb = *(const intx4*)(slots + i + 4);
            uintx4 a0[4], a1[4], b0[4], b1[4];
            #pragma unroll
            for (int e = 0; e < 4; e++) {
                int ia = i + e;
                unsigned idxa = (ia >= st && ia < en) ? (unsigned)qa[e] : (unsigned)V_NODES;
                const char* pa = hbase + (idxa << 7);
                a0[e] = *(const uintx4*)(pa + lg*16);
                a1[e] = *(const uintx4*)(pa + 64 + lg*16);
                int ib = i + 4 + e;
                unsigned idxb = (ib >= st && ib < en) ? (unsigned)qb[e] : (unsigned)V_NODES;
                const char* pb = hbase + (idxb << 7);
                b0[e] = *(const uintx4*)(pb + lg*16);
                b1[e] = *(const uintx4*)(pb + 64 + lg*16);
            }
            #pragma unroll
            for (int e = 0; e < 4; e++) {
                #pragma unroll
                for (int j = 0; j < 4; j++) {
                    mA0[j] = pkmaxu(mA0[j], a0[e][j]);
                    mA1[j] = pkmaxu(mA1[j], a1[e][j]);
                    mB0[j] = pkmaxu(mB0[j], b0[e][j]);
                    mB1[j] = pkmaxu(mB1[j], b1[e][j]);
                }
            }
        }
        bool has = en > st;
        uintx4 d0, d1;
        #pragma unroll
        for (int j = 0; j < 4; j++) {
            unsigned m0 = pkmaxu(mA0[j], mB0[j]);
            unsigned m1 = pkmaxu(mA1[j], mB1[j]);
            d0[j] = has ? decp(m0) : 0u;           // no in-edges -> 0.0
            d1[j] = has ? decp(m1) : 0u;
            r0[j] = decp(r0[j]);
            r1[j] = decp(r1[j]);
        }
        bf16x8 a_agg0 = __builtin_bit_cast(bf16x8, d0);
        bf16x8 a_agg1 = __builtin_bit_cast(bf16x8, d1);
        bf16x8 a_h0   = __builtin_bit_cast(bf16x8, r0);
        bf16x8 a_h1   = __builtin_bit_cast(bf16x8, r1);

        // ---- dual GEMM via MFMA, B-frags from swizzled LDS ----
        f32x4 acc[4];
        #pragma unroll
        for (int cb = 0; cb < 4; cb++) {
            acc[cb] = (f32x4){0.f,0.f,0.f,0.f};
            int wrow = cb*16 + lr;
            int sw   = (wrow & 7) << 4;
            int o0   = (wrow*128 +      lg*16) ^ sw;
            int o1   = (wrow*128 + 64 + lg*16) ^ sw;
            bf16x8 wl0 = *(const bf16x8*)(lds_w + o0);
            bf16x8 wl1 = *(const bf16x8*)(lds_w + o1);
            bf16x8 wr0 = *(const bf16x8*)(lds_w + 8192 + o0);
            bf16x8 wr1 = *(const bf16x8*)(lds_w + 8192 + o1);
            acc[cb] = __builtin_amdgcn_mfma_f32_16x16x32_bf16(a_agg0, wl0, acc[cb], 0,0,0);
            acc[cb] = __builtin_amdgcn_mfma_f32_16x16x32_bf16(a_agg1, wl1, acc[cb], 0,0,0);
            acc[cb] = __builtin_amdgcn_mfma_f32_16x16x32_bf16(a_h0,   wr0, acc[cb], 0,0,0);
            acc[cb] = __builtin_amdgcn_mfma_f32_16x16x32_bf16(a_h1,   wr1, acc[cb], 0,0,0);
        }

        // ---- epilogue: bias + residual + ReLU + write + stats ----
        int g0 = batch[rbase], g15 = batch[rbase + 15];
        if (g0 == g15) {                           // tile-uniform graph (common)
            if (g0 != gc) {
                if (gc >= 0) {
                    #pragma unroll
                    for (int cb = 0; cb < 4; cb++) {
                        atomicAdd(&red_s[(gc<<6) + cb*16 + lr], su[cb]);
                        atomicAdd(&red_q[(gc<<6) + cb*16 + lr], qu[cb]);
                        su[cb] = 0.0f; qu[cb] = 0.0f;
                    }
                }
                gc = g0;
            }
            #pragma unroll
            for (int r = 0; r < 4; r++) {
                int row = rbase + lg*4 + r;
                #pragma unroll
                for (int cb = 0; cb < 4; cb++) {
                    int col = cb*16 + lr;
                    float xv = x[(size_t)row * C_DIM + col];
                    float o  = fmaxf(xv + acc[cb][r] + blv[cb], 0.0f);
                    out[(size_t)row * C_DIM + col] = o;
                    su[cb] += o; qu[cb] = fmaf(o, o, qu[cb]);
                }
            }
        } else {                                   // boundary tile (3 of 20481)
            #pragma unroll
            for (int r = 0; r < 4; r++) {
                int row = rbase + lg*4 + r;
                int g   = batch[row];
                #pragma unroll
                for (int cb = 0; cb < 4; cb++) {
                    int col = cb*16 + lr;
                    float xv = x[(size_t)row * C_DIM + col];
                    float o  = fmaxf(xv + acc[cb][r] + blv[cb], 0.0f);
                    out[(size_t)row * C_DIM + col] = o;
                    int p = (g << 6) | col;
                    atomicAdd(&red_s[p], o);
                    atomicAdd(&red_q[p], o * o);
                }
            }
        }
    }
    if (gc >= 0) {
        #pragma unroll
        for (int cb = 0; cb < 4; cb++) {
            atomicAdd(&red_s[(gc<<6) + cb*16 + lr], su[cb]);
            atomicAdd(&red_q[(gc<<6) + cb*16 + lr], qu[cb]);
        }
    }
    __syncthreads();
    float* row = partial2 + (size_t)blockIdx.x * PW;
    row[threadIdx.x]       = red_s[threadIdx.x];
    row[256 + threadIdx.x] = red_q[threadIdx.x];
}

// ---------------------------------------------------------------------------
// K6: in-place final GraphNorm affine on d_out (float4 vectorized)
// ---------------------------------------------------------------------------
__global__ __launch_bounds__(256) void k_final(float* __restrict__ out,
                                               const int* __restrict__ batch,
                                               const float* __restrict__ scale2,
                                               const float* __restrict__ shift2) {
    __shared__ float sc[256], sh[256];
    sc[threadIdx.x] = scale2[threadIdx.x];
    sh[threadIdx.x] = shift2[threadIdx.x];
    __syncthreads();
    const int total = V_NODES * 16;
    int stride = gridDim.x * 256;
    float4* o4 = (float4*)out;
    for (int i = blockIdx.x * 256 + threadIdx.x; i < total; i += stride) {
        int v  = i >> 4;
        int c4 = (i & 15) << 2;
        int g  = batch[v];
        int p  = (g << 6) | c4;
        float4 val = o4[i];
        val.x = fmaf(val.x, sc[p],   sh[p]);
        val.y = fmaf(val.y, sc[p+1], sh[p+1]);
        val.z = fmaf(val.z, sc[p+2], sh[p+2]);
        val.w = fmaf(val.w, sc[p+3], sh[p+3]);
        o4[i] = val;
    }
}

// ---------------------------------------------------------------------------
extern "C" void kernel_launch(void* const* d_in, const int* in_sizes, int n_in,
                              void* d_out, int out_size, void* d_ws, size_t ws_size,
                              hipStream_t stream) {
    const float* x     = (const float*)d_in[0];
    const int*   ei    = (const int*)  d_in[1];
    const int*   batch = (const int*)  d_in[2];
    const float* n1w   = (const float*)d_in[3];
    const float* n1b   = (const float*)d_in[4];
    const float* n1ms  = (const float*)d_in[5];
    const float* Wl    = (const float*)d_in[6];
    const float* blv   = (const float*)d_in[7];
    const float* Wr    = (const float*)d_in[8];
    const float* n2w   = (const float*)d_in[9];
    const float* n2b   = (const float*)d_in[10];
    const float* n2ms  = (const float*)d_in[11];
    float* out = (float*)d_out;

    // ---- workspace layout (~62 MB) ----
    char* w = (char*)d_ws;
    unsigned short* henc = (unsigned short*)w; w += (size_t)(V_NODES + 1) * C_DIM * 2; // +dummy row (zeroed)
    int* slots           = (int*)w;            w += (size_t)E_EDGES * 4 + 64;          // +pad for quad prefetch
    int* hist            = (int*)w;            w += (size_t)V_NODES * 4;
    int* offs            = (int*)w;            w += (size_t)(V_NODES + 1) * 4 + 12;
    unsigned short* rank = (unsigned short*)w; w += (size_t)E_EDGES * 2;
    int* bsum            = (int*)w;            w += 1536 * 4;
    char* gWsw           = w;                  w += 16384;
    float* partial1      = (float*)w;          w += (size_t)STAT_BLOCKS * PW * 4;      // 1.06 MB
    float* partial2      = (float*)w;          w += (size_t)SAGE_BLOCKS * PW * 4;      // 4.26 MB
    float* stats  = (float*)w;
    float* sum1   = stats;          // 256
    float* sumsq1 = stats + 256;    // 256
    float* cnt    = stats + 512;    // 4 (+pad 60)
    float* sum2   = stats + 576;    // 256
    float* sumsq2 = stats + 832;    // 256
    float* scale1 = stats + 1088;
    float* shift1 = stats + 1344;
    float* scale2 = stats + 1600;
    float* shift2 = stats + 1856;   // end 2112 floats

    hipMemsetAsync(henc + (size_t)V_NODES * C_DIM, 0, C_DIM * 2, stream); // dummy row = enc-bottom

    k1      <<<HIST_BLOCKS + STAT_BLOCKS, K1_THREADS, 0, stream>>>(x, batch, ei, rank, hist, partial1);
    k_scan1 <<<NB_SCAN, 256, 0, stream>>>(hist, bsum);
    k_red   <<<129, 256, 0, stream>>>(partial1, STAT_BLOCKS, 516, sum1, cnt);
    k_params<<<2,   256, 0, stream>>>(sum1, sumsq1, cnt, n1w, n1b, n1ms,
                                      scale1, shift1, Wl, Wr, gWsw, 1, bsum);
    k_scan3 <<<NB_SCAN, 256, 0, stream>>>(hist, bsum, offs);
    k_h_fill<<<FILL_BLOCKS + H_BLOCKS, 256, 0, stream>>>(x, batch, scale1, shift1,
                                      henc, ei, rank, offs, slots);
    k_sage  <<<SAGE_BLOCKS, 256, 0, stream>>>(henc, x, batch, offs, slots,
                                      gWsw, blv, out, partial2);
    k_red   <<<128, 256, 0, stream>>>(partial2, SAGE_BLOCKS, 512, sum2, cnt);
    k_params<<<1,   256, 0, stream>>>(sum2, sumsq2, cnt, n2w, n2b, n2ms,
                                      scale2, shift2, (const float*)0, (const float*)0,
                                      (char*)0, 0, (int*)0);
    k_final <<<2048, 256, 0, stream>>>(out, batch, scale2, shift2);
}

// Round 8
// 358.561 us; speedup vs baseline: 1.6358x; 1.6358x over previous
//
#include <hip/hip_runtime.h>

#define V_NODES 327696
#define E_EDGES 1966080
#define C_DIM   64
#define G_NUM   4
#define EPS_GN  1e-5f
#define N_TILES (V_NODES/16)      // 20481 exact
#define SAGE_BLOCKS 2048
#define WAVES_TOTAL (SAGE_BLOCKS*4)
#define FILL_BLOCKS 512
#define H_BLOCKS 2048
#define NB_SCAN 1281              // ceil(V/256)
#define CH_SCAN2 6                // ceil(NB_SCAN/256)
#define PW 520                    // partial row width (floats)
#define STAT_BLOCKS 2048
#define STAT_WAVES (STAT_BLOCKS*4)     // 8192
#define TOTAL_F4 (V_NODES*16)          // 5243136 float4 chunks
#define SW_CHUNK 640                   // float4s per wave (40 nodes)
#define HIST_BLOCKS 960                // 960*256*4 = 983040 = E/2

typedef short bf16x8 __attribute__((ext_vector_type(8)));
typedef float f32x4  __attribute__((ext_vector_type(4)));
typedef unsigned uintx4 __attribute__((ext_vector_type(4)));
typedef int intx4 __attribute__((ext_vector_type(4)));
typedef unsigned short u16x2 __attribute__((ext_vector_type(2)));

__device__ __forceinline__ unsigned short f2bf(float f) {   // RNE f32 -> bf16
    unsigned u = __float_as_uint(f);
    return (unsigned short)((u + 0x7FFFu + ((u >> 16) & 1u)) >> 16);
}
// monotone-u16 encoding of bf16 bits: order(enc)==order(value)
__device__ __forceinline__ unsigned short encbf(float f) {
    unsigned short b = f2bf(f);
    return b ^ (unsigned short)(0x8000u | ((b >> 15) * 0x7FFFu));
}
__device__ __forceinline__ unsigned decp(unsigned e) {      // packed decode x2
    unsigned s = e & 0x80008000u;
    unsigned m = (s >> 15) * 0x7FFFu;
    return e ^ ~m;
}
__device__ __forceinline__ unsigned pkmaxu(unsigned a, unsigned b) {
    u16x2 xa = __builtin_bit_cast(u16x2, a);
    u16x2 xb = __builtin_bit_cast(u16x2, b);
    u16x2 r  = __builtin_elementwise_max(xa, xb);           // v_pk_max_u16
    return __builtin_bit_cast(unsigned, r);
}

// ---------------------------------------------------------------------------
// k_stats: per-(g,c) sum/sumsq/count of x. Wave-contiguous 640-float4 regions;
// graph-uniform waves (8189/8192) take a fully-unrolled branch-free path with
// 10 independent float4 loads in flight. No global atomics (partial rows).
// ---------------------------------------------------------------------------
__global__ __launch_bounds__(256) void k_stats(const float* __restrict__ x,
                                               const int* __restrict__ batch,
                                               float* __restrict__ partial1) {
    __shared__ float red_s[256], red_q[256], red_c[G_NUM];
    const int t = threadIdx.x;
    red_s[t] = 0.0f; red_q[t] = 0.0f;
    if (t < G_NUM) red_c[t] = 0.0f;
    __syncthreads();

    const int w    = blockIdx.x * 4 + (t >> 6);
    const int lane = t & 63;
    const int base = w * SW_CHUNK;                       // %16==0
    const int end  = (w == STAT_WAVES - 1) ? TOTAL_F4 : base + SW_CHUNK;
    const int c4   = (lane & 15) << 2;
    const bool cntr = (lane & 15) == 0;
    const float4* x4p = (const float4*)x;

    const int g0 = batch[base >> 4];
    const int g1 = batch[(end - 1) >> 4];

    if (g0 == g1 && end == base + SW_CHUNK) {
        // ---- fast path: compile-time 10 iterations, no branches/atomics ----
        float4 su = {0,0,0,0}, qu = {0,0,0,0};
        #pragma unroll
        for (int it = 0; it < 10; it++) {
            float4 v = x4p[base + lane + it * 64];
            su.x += v.x; su.y += v.y; su.z += v.z; su.w += v.w;
            qu.x = fmaf(v.x, v.x, qu.x); qu.y = fmaf(v.y, v.y, qu.y);
            qu.z = fmaf(v.z, v.z, qu.z); qu.w = fmaf(v.w, v.w, qu.w);
        }
        int p = (g0 << 6) + c4;
        atomicAdd(&red_s[p],   su.x); atomicAdd(&red_q[p],   qu.x);
        atomicAdd(&red_s[p+1], su.y); atomicAdd(&red_q[p+1], qu.y);
        atomicAdd(&red_s[p+2], su.z); atomicAdd(&red_q[p+2], qu.z);
        atomicAdd(&red_s[p+3], su.w); atomicAdd(&red_q[p+3], qu.w);
        if (cntr) atomicAdd(&red_c[g0], 10.0f);
    } else {
        // ---- slow path: boundary or tail wave (<=4 waves total) ----
        for (int idx = base + lane; idx < end; idx += 64) {
            float4 v = x4p[idx];
            int g = batch[idx >> 4];
            int p = (g << 6) + c4;
            atomicAdd(&red_s[p],   v.x); atomicAdd(&red_q[p],   v.x * v.x);
            atomicAdd(&red_s[p+1], v.y); atomicAdd(&red_q[p+1], v.y * v.y);
            atomicAdd(&red_s[p+2], v.z); atomicAdd(&red_q[p+2], v.z * v.z);
            atomicAdd(&red_s[p+3], v.w); atomicAdd(&red_q[p+3], v.w * v.w);
            if (cntr) atomicAdd(&red_c[g], 1.0f);
        }
    }
    __syncthreads();
    float* row = partial1 + (size_t)blockIdx.x * PW;
    row[t] = red_s[t]; row[256 + t] = red_q[t];
    if (t < G_NUM) row[512 + t] = red_c[t];
}

// ---------------------------------------------------------------------------
// k_hist: in-degree histogram + per-edge rank. 8 edges/thread: 2 coalesced
// intx4 loads, then 8 INDEPENDENT atomicAdd-with-return in flight, 8 writes.
// ---------------------------------------------------------------------------
__global__ __launch_bounds__(256) void k_hist(const int* __restrict__ ei,
                                              int* __restrict__ hist,
                                              unsigned short* __restrict__ rank) {
    const int t = blockIdx.x * 256 + threadIdx.x;
    const int* dst = ei + E_EDGES;
    const int e0 = t * 4;                    // pass 0
    const int e1 = (E_EDGES / 2) + t * 4;    // pass 1
    intx4 a = *(const intx4*)(dst + e0);
    intx4 b = *(const intx4*)(dst + e1);
    int r0 = atomicAdd(&hist[a[0]], 1);
    int r1 = atomicAdd(&hist[a[1]], 1);
    int r2 = atomicAdd(&hist[a[2]], 1);
    int r3 = atomicAdd(&hist[a[3]], 1);
    int r4 = atomicAdd(&hist[b[0]], 1);
    int r5 = atomicAdd(&hist[b[1]], 1);
    int r6 = atomicAdd(&hist[b[2]], 1);
    int r7 = atomicAdd(&hist[b[3]], 1);
    ushort4 wa = { (unsigned short)r0, (unsigned short)r1,
                   (unsigned short)r2, (unsigned short)r3 };
    ushort4 wb = { (unsigned short)r4, (unsigned short)r5,
                   (unsigned short)r6, (unsigned short)r7 };
    *(ushort4*)(rank + e0) = wa;
    *(ushort4*)(rank + e1) = wb;
}

// ---------------------------------------------------------------------------
// k_red: reduce partial rows -> sums (wave per entry, coalesced-in-e reads)
// ---------------------------------------------------------------------------
__global__ __launch_bounds__(256) void k_red(const float* __restrict__ partial,
                                             int nblocks, int nent,
                                             float* __restrict__ outs,
                                             float* __restrict__ outc) {
    int e = blockIdx.x * 4 + (threadIdx.x >> 6);
    int lane = threadIdx.x & 63;
    if (e >= nent) return;
    float s = 0.0f;
    for (int b = lane; b < nblocks; b += 64) s += partial[(size_t)b * PW + e];
    #pragma unroll
    for (int off = 1; off < 64; off <<= 1) s += __shfl_xor(s, off);
    if (lane == 0) { if (e < 512) outs[e] = s; else outc[e - 512] = s; }
}

// ---------------------------------------------------------------------------
// Scan level 1: per-block (256-entry) sums of hist
// ---------------------------------------------------------------------------
__global__ __launch_bounds__(256) void k_scan1(const int* __restrict__ hist,
                                               int* __restrict__ bsum) {
    __shared__ int s[256];
    int i = blockIdx.x * 256 + threadIdx.x;
    s[threadIdx.x] = (i < V_NODES) ? hist[i] : 0;
    __syncthreads();
    for (int off = 128; off > 0; off >>= 1) {
        if (threadIdx.x < off) s[threadIdx.x] += s[threadIdx.x + off];
        __syncthreads();
    }
    if (threadIdx.x == 0) bsum[blockIdx.x] = s[0];
}

// ---------------------------------------------------------------------------
// K2: block 0 = GraphNorm affine fold (+ optional swizzled weight prep);
//     block 1 (if launched) = exclusive scan of the 1281 block sums
// ---------------------------------------------------------------------------
__global__ __launch_bounds__(256) void k_params(const float* __restrict__ sum,
                                                const float* __restrict__ sumsq,
                                                const float* __restrict__ cnt,
                                                const float* __restrict__ w,
                                                const float* __restrict__ b,
                                                const float* __restrict__ ms,
                                                float* __restrict__ scale,
                                                float* __restrict__ shift,
                                                const float* __restrict__ Wl,
                                                const float* __restrict__ Wr,
                                                char* __restrict__ gWsw,
                                                int do_wt,
                                                int* __restrict__ bsum) {
    if (blockIdx.x == 0) {
        int t = threadIdx.x;            // t = g*64 + c
        int g = t >> 6, c = t & 63;
        float n    = cnt[g];
        float mean = sum[t] / n;
        float msq  = sumsq[t] / n;
        float m    = ms[c];
        float var  = msq - 2.0f*m*mean*mean + m*m*mean*mean;
        float inv  = rsqrtf(var + EPS_GN);
        float sc   = w[c] * inv;
        scale[t] = sc;
        shift[t] = b[c] - mean * m * sc;
        if (do_wt) {
            for (int i = threadIdx.x; i < C_DIM*C_DIM; i += 256) {
                int k = i >> 6, col = i & 63;          // W[k][col]
                int boff = (col*128 + k*2) ^ ((col & 7) << 4);
                *(unsigned short*)(gWsw + boff)        = f2bf(Wl[i]);
                *(unsigned short*)(gWsw + 8192 + boff) = f2bf(Wr[i]);
            }
        }
    } else {                            // scan of bsum[0..NB_SCAN)
        __shared__ int s[256];
        int t = threadIdx.x;
        int loc[CH_SCAN2];
        int mysum = 0;
        #pragma unroll
        for (int j = 0; j < CH_SCAN2; j++) {
            int idx = t * CH_SCAN2 + j;
            loc[j] = (idx < NB_SCAN) ? bsum[idx] : 0;
            mysum += loc[j];
        }
        s[t] = mysum;
        __syncthreads();
        for (int off = 1; off < 256; off <<= 1) {      // Hillis-Steele inclusive
            int tmp = (t >= off) ? s[t - off] : 0;
            __syncthreads();
            s[t] += tmp;
            __syncthreads();
        }
        int ex = s[t] - mysum;                          // exclusive prefix
        #pragma unroll
        for (int j = 0; j < CH_SCAN2; j++) {
            int idx = t * CH_SCAN2 + j;
            if (idx < NB_SCAN) { bsum[idx] = ex; ex += loc[j]; }
        }
    }
}

// ---------------------------------------------------------------------------
// Scan level 3: per-block exclusive scan + block offset -> offs
// ---------------------------------------------------------------------------
__global__ __launch_bounds__(256) void k_scan3(const int* __restrict__ hist,
                                               const int* __restrict__ bsum,
                                               int* __restrict__ offs) {
    __shared__ int s[256];
    int t = threadIdx.x;
    int i = blockIdx.x * 256 + t;
    int v = (i < V_NODES) ? hist[i] : 0;
    s[t] = v;
    __syncthreads();
    for (int off = 1; off < 256; off <<= 1) {
        int tmp = (t >= off) ? s[t - off] : 0;
        __syncthreads();
        s[t] += tmp;
        __syncthreads();
    }
    int ex = s[t] - v + bsum[blockIdx.x];
    if (i < V_NODES) offs[i] = ex;
    if (i == 0) offs[V_NODES] = E_EDGES;
}

// ---------------------------------------------------------------------------
// K3 (merged): blocks [0,FILL_BLOCKS) do atomic-free CSR fill via rank;
//              blocks [FILL_BLOCKS, ...) compute henc = enc(bf16(norm1(x)))
// ---------------------------------------------------------------------------
__global__ __launch_bounds__(256) void k_h_fill(const float* __restrict__ x,
                                                const int* __restrict__ batch,
                                                const float* __restrict__ scale1,
                                                const float* __restrict__ shift1,
                                                unsigned short* __restrict__ henc,
                                                const int* __restrict__ ei,
                                                const unsigned short* __restrict__ rank,
                                                const int* __restrict__ offs,
                                                int* __restrict__ slots) {
    if (blockIdx.x < FILL_BLOCKS) {
        int stride = FILL_BLOCKS * 256;
        for (int e = blockIdx.x * 256 + threadIdx.x; e < E_EDGES; e += stride) {
            int src = ei[e];
            int d   = ei[E_EDGES + e];
            slots[offs[d] + (int)rank[e]] = src;
        }
        return;
    }
    __shared__ float sc[256], sh[256];
    sc[threadIdx.x] = scale1[threadIdx.x];
    sh[threadIdx.x] = shift1[threadIdx.x];
    __syncthreads();
    const int total = V_NODES * 16;           // float4 chunks
    int bid = blockIdx.x - FILL_BLOCKS;
    int stride = H_BLOCKS * 256;
    const float4* x4 = (const float4*)x;
    ushort4* h4 = (ushort4*)henc;
    for (int i = bid * 256 + threadIdx.x; i < total; i += stride) {
        int v  = i >> 4;
        int c4 = (i & 15) << 2;
        int g  = batch[v];
        int p  = (g << 6) | c4;
        float4 val = x4[i];
        ushort4 o;
        o.x = encbf(fmaf(val.x, sc[p],   sh[p]));
        o.y = encbf(fmaf(val.y, sc[p+1], sh[p+1]));
        o.z = encbf(fmaf(val.z, sc[p+2], sh[p+2]));
        o.w = encbf(fmaf(val.w, sc[p+3], sh[p+3]));
        h4[i] = o;
    }
}

// ---------------------------------------------------------------------------
// K4: fused gather-max + dual GEMM (MFMA) + residual/ReLU + stats2 partials.
// ---------------------------------------------------------------------------
__global__ __launch_bounds__(256) void k_sage(const unsigned short* __restrict__ henc,
                                              const float* __restrict__ x,
                                              const int* __restrict__ batch,
                                              const int* __restrict__ offs,
                                              const int* __restrict__ slots,
                                              const char* __restrict__ gWsw,
                                              const float* __restrict__ bl,
                                              float* __restrict__ out,
                                              float* __restrict__ partial2) {
    __shared__ char lds_w[16384];          // Wl swizzled at 0, Wr at 8192
    __shared__ float red_s[256], red_q[256];
    {
        const float4* wsrc = (const float4*)gWsw;
        float4* wdst = (float4*)lds_w;
        for (int t = threadIdx.x; t < 1024; t += 256) wdst[t] = wsrc[t];
    }
    red_s[threadIdx.x] = 0.0f; red_q[threadIdx.x] = 0.0f;
    __syncthreads();

    const int lane = threadIdx.x & 63;
    const int wid  = threadIdx.x >> 6;
    const int lg = lane >> 4, lr = lane & 15;
    const char* hbase = (const char*)henc;

    float blv[4];
    #pragma unroll
    for (int cb = 0; cb < 4; cb++) blv[cb] = bl[cb*16 + lr];

    float su[4] = {0,0,0,0}, qu[4] = {0,0,0,0};
    int gc = -1;

    const int gwave = blockIdx.x * 4 + wid;
    for (int tile = gwave; tile < N_TILES; tile += WAVES_TOTAL) {
        const int rbase = tile << 4;
        const int myrow = rbase + lr;
        int st = offs[myrow];
        int en = offs[myrow + 1];

        // root-h loads early (independent of gather)
        const char* hr = hbase + ((unsigned)myrow << 7);
        uintx4 r0 = *(const uintx4*)(hr + lg*16);
        uintx4 r1 = *(const uintx4*)(hr + 64 + lg*16);

        // ---- gather-max: 8 edges/row/step, 16 h-loads in flight ----
        uintx4 mA0 = {0,0,0,0}, mA1 = {0,0,0,0};
        uintx4 mB0 = {0,0,0,0}, mB1 = {0,0,0,0};
        for (int i = st & ~7; __ballot(i < en) != 0ull; i += 8) {
            intx4 qa = *(const intx4*)(slots + i);
            intx4 qb = *(const intx4*)(slots + i + 4);
            uintx4 a0[4], a1[4], b0[4], b1[4];
            #pragma unroll
            for (int e = 0; e < 4; e++) {
                int ia = i + e;
                unsigned idxa = (ia >= st && ia < en) ? (unsigned)qa[e] : (unsigned)V_NODES;
                const char* pa = hbase + (idxa << 7);
                a0[e] = *(const uintx4*)(pa + lg*16);
                a1[e] = *(const uintx4*)(pa + 64 + lg*16);
                int ib = i + 4 + e;
                unsigned idxb = (ib >= st && ib < en) ? (unsigned)qb[e] : (unsigned)V_NODES;
                const char* pb = hbase + (idxb << 7);
                b0[e] = *(const uintx4*)(pb + lg*16);
                b1[e] = *(const uintx4*)(pb + 64 + lg*16);
            }
            #pragma unroll
            for (int e = 0; e < 4; e++) {
                #pragma unroll
                for (int j = 0; j < 4; j++) {
                    mA0[j] = pkmaxu(mA0[j], a0[e][j]);
                    mA1[j] = pkmaxu(mA1[j], a1[e][j]);
                    mB0[j] = pkmaxu(mB0[j], b0[e][j]);
                    mB1[j] = pkmaxu(mB1[j], b1[e][j]);
                }
            }
        }
        bool has = en > st;
        uintx4 d0, d1;
        #pragma unroll
        for (int j = 0; j < 4; j++) {
            unsigned m0 = pkmaxu(mA0[j], mB0[j]);
            unsigned m1 = pkmaxu(mA1[j], mB1[j]);
            d0[j] = has ? decp(m0) : 0u;           // no in-edges -> 0.0
            d1[j] = has ? decp(m1) : 0u;
            r0[j] = decp(r0[j]);
            r1[j] = decp(r1[j]);
        }
        bf16x8 a_agg0 = __builtin_bit_cast(bf16x8, d0);
        bf16x8 a_agg1 = __builtin_bit_cast(bf16x8, d1);
        bf16x8 a_h0   = __builtin_bit_cast(bf16x8, r0);
        bf16x8 a_h1   = __builtin_bit_cast(bf16x8, r1);

        // ---- dual GEMM via MFMA, B-frags from swizzled LDS ----
        f32x4 acc[4];
        #pragma unroll
        for (int cb = 0; cb < 4; cb++) {
            acc[cb] = (f32x4){0.f,0.f,0.f,0.f};
            int wrow = cb*16 + lr;
            int sw   = (wrow & 7) << 4;
            int o0   = (wrow*128 +      lg*16) ^ sw;
            int o1   = (wrow*128 + 64 + lg*16) ^ sw;
            bf16x8 wl0 = *(const bf16x8*)(lds_w + o0);
            bf16x8 wl1 = *(const bf16x8*)(lds_w + o1);
            bf16x8 wr0 = *(const bf16x8*)(lds_w + 8192 + o0);
            bf16x8 wr1 = *(const bf16x8*)(lds_w + 8192 + o1);
            acc[cb] = __builtin_amdgcn_mfma_f32_16x16x32_bf16(a_agg0, wl0, acc[cb], 0,0,0);
            acc[cb] = __builtin_amdgcn_mfma_f32_16x16x32_bf16(a_agg1, wl1, acc[cb], 0,0,0);
            acc[cb] = __builtin_amdgcn_mfma_f32_16x16x32_bf16(a_h0,   wr0, acc[cb], 0,0,0);
            acc[cb] = __builtin_amdgcn_mfma_f32_16x16x32_bf16(a_h1,   wr1, acc[cb], 0,0,0);
        }

        // ---- epilogue: bias + residual + ReLU + write + stats ----
        int g0 = batch[rbase], g15 = batch[rbase + 15];
        if (g0 == g15) {                           // tile-uniform graph (common)
            if (g0 != gc) {
                if (gc >= 0) {
                    #pragma unroll
                    for (int cb = 0; cb < 4; cb++) {
                        atomicAdd(&red_s[(gc<<6) + cb*16 + lr], su[cb]);
                        atomicAdd(&red_q[(gc<<6) + cb*16 + lr], qu[cb]);
                        su[cb] = 0.0f; qu[cb] = 0.0f;
                    }
                }
                gc = g0;
            }
            #pragma unroll
            for (int r = 0; r < 4; r++) {
                int row = rbase + lg*4 + r;
                #pragma unroll
                for (int cb = 0; cb < 4; cb++) {
                    int col = cb*16 + lr;
                    float xv = x[(size_t)row * C_DIM + col];
                    float o  = fmaxf(xv + acc[cb][r] + blv[cb], 0.0f);
                    out[(size_t)row * C_DIM + col] = o;
                    su[cb] += o; qu[cb] = fmaf(o, o, qu[cb]);
                }
            }
        } else {                                   // boundary tile (3 of 20481)
            #pragma unroll
            for (int r = 0; r < 4; r++) {
                int row = rbase + lg*4 + r;
                int g   = batch[row];
                #pragma unroll
                for (int cb = 0; cb < 4; cb++) {
                    int col = cb*16 + lr;
                    float xv = x[(size_t)row * C_DIM + col];
                    float o  = fmaxf(xv + acc[cb][r] + blv[cb], 0.0f);
                    out[(size_t)row * C_DIM + col] = o;
                    int p = (g << 6) | col;
                    atomicAdd(&red_s[p], o);
                    atomicAdd(&red_q[p], o * o);
                }
            }
        }
    }
    if (gc >= 0) {
        #pragma unroll
        for (int cb = 0; cb < 4; cb++) {
            atomicAdd(&red_s[(gc<<6) + cb*16 + lr], su[cb]);
            atomicAdd(&red_q[(gc<<6) + cb*16 + lr], qu[cb]);
        }
    }
    __syncthreads();
    float* row = partial2 + (size_t)blockIdx.x * PW;
    row[threadIdx.x]       = red_s[threadIdx.x];
    row[256 + threadIdx.x] = red_q[threadIdx.x];
}

// ---------------------------------------------------------------------------
// K6: in-place final GraphNorm affine on d_out (float4 vectorized)
// ---------------------------------------------------------------------------
__global__ __launch_bounds__(256) void k_final(float* __restrict__ out,
                                               const int* __restrict__ batch,
                                               const float* __restrict__ scale2,
                                               const float* __restrict__ shift2) {
    __shared__ float sc[256], sh[256];
    sc[threadIdx.x] = scale2[threadIdx.x];
    sh[threadIdx.x] = shift2[threadIdx.x];
    __syncthreads();
    const int total = V_NODES * 16;
    int stride = gridDim.x * 256;
    float4* o4 = (float4*)out;
    for (int i = blockIdx.x * 256 + threadIdx.x; i < total; i += stride) {
        int v  = i >> 4;
        int c4 = (i & 15) << 2;
        int g  = batch[v];
        int p  = (g << 6) | c4;
        float4 val = o4[i];
        val.x = fmaf(val.x, sc[p],   sh[p]);
        val.y = fmaf(val.y, sc[p+1], sh[p+1]);
        val.z = fmaf(val.z, sc[p+2], sh[p+2]);
        val.w = fmaf(val.w, sc[p+3], sh[p+3]);
        o4[i] = val;
    }
}

// ---------------------------------------------------------------------------
extern "C" void kernel_launch(void* const* d_in, const int* in_sizes, int n_in,
                              void* d_out, int out_size, void* d_ws, size_t ws_size,
                              hipStream_t stream) {
    const float* x     = (const float*)d_in[0];
    const int*   ei    = (const int*)  d_in[1];
    const int*   batch = (const int*)  d_in[2];
    const float* n1w   = (const float*)d_in[3];
    const float* n1b   = (const float*)d_in[4];
    const float* n1ms  = (const float*)d_in[5];
    const float* Wl    = (const float*)d_in[6];
    const float* blv   = (const float*)d_in[7];
    const float* Wr    = (const float*)d_in[8];
    const float* n2w   = (const float*)d_in[9];
    const float* n2b   = (const float*)d_in[10];
    const float* n2ms  = (const float*)d_in[11];
    float* out = (float*)d_out;

    // ---- workspace layout (~66 MB; ws >= 84 MB proven in round 1) ----
    char* w = (char*)d_ws;
    unsigned short* henc = (unsigned short*)w; w += (size_t)(V_NODES + 1) * C_DIM * 2; // +dummy row (zeroed)
    int* slots           = (int*)w;            w += (size_t)E_EDGES * 4 + 64;          // +pad for quad prefetch
    int* hist            = (int*)w;            w += (size_t)V_NODES * 4;
    int* offs            = (int*)w;            w += (size_t)(V_NODES + 1) * 4 + 12;
    unsigned short* rank = (unsigned short*)w; w += (size_t)E_EDGES * 2;
    int* bsum            = (int*)w;            w += 1536 * 4;
    char* gWsw           = w;                  w += 16384;
    float* partial1      = (float*)w;          w += (size_t)STAT_BLOCKS * PW * 4;      // 4.26 MB
    float* partial2      = (float*)w;          w += (size_t)SAGE_BLOCKS * PW * 4;      // 4.26 MB
    float* stats  = (float*)w;
    float* sum1   = stats;          // 256
    float* sumsq1 = stats + 256;    // 256
    float* cnt    = stats + 512;    // 4 (+pad 60)
    float* sum2   = stats + 576;    // 256
    float* sumsq2 = stats + 832;    // 256
    float* scale1 = stats + 1088;
    float* shift1 = stats + 1344;
    float* scale2 = stats + 1600;
    float* shift2 = stats + 1856;   // end 2112 floats

    hipMemsetAsync(hist, 0, (size_t)V_NODES * sizeof(int), stream);
    hipMemsetAsync(henc + (size_t)V_NODES * C_DIM, 0, C_DIM * 2, stream); // dummy row = enc-bottom

    k_stats <<<STAT_BLOCKS, 256, 0, stream>>>(x, batch, partial1);
    k_hist  <<<HIST_BLOCKS, 256, 0, stream>>>(ei, hist, rank);
    k_red   <<<129, 256, 0, stream>>>(partial1, STAT_BLOCKS, 516, sum1, cnt);
    k_scan1 <<<NB_SCAN, 256, 0, stream>>>(hist, bsum);
    k_params<<<2,   256, 0, stream>>>(sum1, sumsq1, cnt, n1w, n1b, n1ms,
                                      scale1, shift1, Wl, Wr, gWsw, 1, bsum);
    k_scan3 <<<NB_SCAN, 256, 0, stream>>>(hist, bsum, offs);
    k_h_fill<<<FILL_BLOCKS + H_BLOCKS, 256, 0, stream>>>(x, batch, scale1, shift1,
                                      henc, ei, rank, offs, slots);
    k_sage  <<<SAGE_BLOCKS, 256, 0, stream>>>(henc, x, batch, offs, slots,
                                      gWsw, blv, out, partial2);
    k_red   <<<128, 256, 0, stream>>>(partial2, SAGE_BLOCKS, 512, sum2, cnt);
    k_params<<<1,   256, 0, stream>>>(sum2, sumsq2, cnt, n2w, n2b, n2ms,
                                      scale2, shift2, (const float*)0, (const float*)0,
                                      (char*)0, 0, (int*)0);
    k_final <<<2048, 256, 0, stream>>>(out, batch, scale2, shift2);
}